// Round 13
// baseline (263.177 us; speedup 1.0000x reference)
//
#include <hip/hip_runtime.h>
#include <hip/hip_fp16.h>

typedef _Float16 f16x4  __attribute__((ext_vector_type(4)));
typedef float    f32x16 __attribute__((ext_vector_type(16)));

constexpr int Nn = 8192;
constexpr int Dd = 256;

constexpr int BM  = 256;        // I-rows per GEMM block
constexpr int KC  = 1024;       // K range per block
constexpr int SK  = 64;         // K subchunk (64 B of fp8 per row)
constexpr int NSC = KC / SK;    // 16 subchunks
constexpr int ABYTES = BM * SK; // 16 KB per A buffer (fp8)

#define AS1 __attribute__((address_space(1)))
#define AS3 __attribute__((address_space(3)))
#define WAITV(N) asm volatile("s_waitcnt vmcnt(" #N ")" ::: "memory")

// ---------------------------------------------------------------------------
// K1: rowsum of A -> dis = rsqrt(sum+1e-10), rd = sqrt(sum+1e-10);
//     writes Af8 = e4m3(A) (64 MB). Zeroes s/T/cnt. At BW floor (6.27 TB/s).
__global__ __launch_bounds__(256) void k_rowcvt(const float* __restrict__ A,
                                                unsigned char* __restrict__ Af8,
                                                float* __restrict__ dis,
                                                float* __restrict__ rd,
                                                float* __restrict__ s,
                                                float* __restrict__ T,
                                                unsigned int* __restrict__ cnt) {
    if (blockIdx.x == 0) {
        if (threadIdx.x == 0) { *T = 0.f; *cnt = 0u; }
        s[threadIdx.x] = 0.f;
    }
    const int row  = blockIdx.x * 4 + (threadIdx.x >> 6);
    const int lane = threadIdx.x & 63;
    const float4*  rp = reinterpret_cast<const float4*>(A + (size_t)row * Nn);
    unsigned int*  wp = reinterpret_cast<unsigned int*>(Af8 + (size_t)row * Nn);
    float sum = 0.f;
    #pragma unroll
    for (int i = 0; i < Nn / 256; ++i) {
        float4 v = rp[i * 64 + lane];
        sum += (v.x + v.y) + (v.z + v.w);
        int p = __builtin_amdgcn_cvt_pk_fp8_f32(v.x, v.y, 0, false);
        p     = __builtin_amdgcn_cvt_pk_fp8_f32(v.z, v.w, p, true);
        wp[i * 64 + lane] = (unsigned int)p;
    }
    #pragma unroll
    for (int off = 32; off > 0; off >>= 1) sum += __shfl_down(sum, off, 64);
    if (lane == 0) {
        float rs = sum + 1e-10f;
        dis[row] = rsqrtf(rs);
        rd[row]  = sqrtf(rs);
    }
}

// ---------------------------------------------------------------------------
// K2: Y = dis * Z/||Z||. Writes Ytf8[256 n][8192 i] = e4m3(64*Y) and
//     Yr[8192][256] f16 (true Y, for epilogue + colsum).
__global__ __launch_bounds__(256) void k_makeYt(const float* __restrict__ Z,
                                               const float* __restrict__ dis,
                                               unsigned char* __restrict__ Ytf8,
                                               _Float16* __restrict__ Yr) {
    __shared__ float nrm[64][4];
    __shared__ unsigned char tile[Dd][80];
    const int t = threadIdx.x;
    const int r = t >> 2, q = t & 3;
    const int row = blockIdx.x * 64 + r;
    const float4* zp = reinterpret_cast<const float4*>(Z + (size_t)row * Dd + q * 64);
    float4 v[16];
    float ss = 0.f;
    #pragma unroll
    for (int i = 0; i < 16; ++i) {
        v[i] = zp[i];
        ss += v[i].x*v[i].x + v[i].y*v[i].y + v[i].z*v[i].z + v[i].w*v[i].w;
    }
    nrm[r][q] = ss;
    __syncthreads();
    const float tot  = nrm[r][0] + nrm[r][1] + nrm[r][2] + nrm[r][3];
    const float sc   = dis[row] / fmaxf(sqrtf(tot), 1e-12f);
    const float sc8  = 64.f * sc;
    #pragma unroll
    for (int i = 0; i < 16; ++i) {
        const int c0 = q * 64 + i * 4;
        f16x4 y = { (_Float16)(v[i].x * sc), (_Float16)(v[i].y * sc),
                    (_Float16)(v[i].z * sc), (_Float16)(v[i].w * sc) };
        *reinterpret_cast<f16x4*>(Yr + (size_t)row * Dd + c0) = y;
        int p = __builtin_amdgcn_cvt_pk_fp8_f32(v[i].x * sc8, v[i].y * sc8, 0, false);
        p     = __builtin_amdgcn_cvt_pk_fp8_f32(v[i].z * sc8, v[i].w * sc8, p, true);
        tile[c0+0][r] = (unsigned char)(p);
        tile[c0+1][r] = (unsigned char)(p >> 8);
        tile[c0+2][r] = (unsigned char)(p >> 16);
        tile[c0+3][r] = (unsigned char)(p >> 24);
    }
    __syncthreads();
    int4*       dst = reinterpret_cast<int4*>(Ytf8 + (size_t)t * Nn + blockIdx.x * 64);
    const int4* src = reinterpret_cast<const int4*>(&tile[t][0]);
    #pragma unroll
    for (int i = 0; i < 4; ++i) dst[i] = src[i];
}

// ---------------------------------------------------------------------------
// K2b: s[k] = sum_j Zn[j][k] = sum_j Yr[j][k] * rd[j]
__global__ __launch_bounds__(256) void k_colsum(const _Float16* __restrict__ Yr,
                                                const float* __restrict__ rd,
                                                float* __restrict__ s) {
    const int c  = threadIdx.x;
    const int r0 = blockIdx.x * 256;
    float acc = 0.f;
    const _Float16* yp = Yr + (size_t)r0 * Dd + c;
    #pragma unroll 8
    for (int r = 0; r < 256; ++r) acc += (float)yp[(size_t)r * Dd] * rd[r0 + r];
    atomicAdd(&s[c], acc);
}

// ---------------------------------------------------------------------------
// K3: T += sum_i Y_i . (A[I,Kchunk] @ Y[Kchunk])   [32x32x16 fp8 MFMA]
// Round-13: B-fragments read DIRECTLY from global Ytf8 (2 MB: L2-resident;
// per-subchunk block footprint 16 KB: L1-resident with 32x line reuse) --
// removes Yt from the LDS/barrier path. Only A staged via global_load_lds
// (1 shot/wave/sc, NB=3, 2 ahead). The per-iteration STAGE is issued as the
// LAST VMEM of the iteration so compiler bf-waits never drain the prefetch:
// no manual vmcnt in the loop, ONE barrier per subchunk.
// fp8 32x32x16 fragments: A row=l&31, k=(l>>5)*8+byte; B col=l&31 same k;
// D col=l&31, row=(reg&3)+8*(reg>>2)+4*(l>>5). Yt holds 64*Y -> 1/64 at end.
__global__ __launch_bounds__(1024, 4) void k_main(const unsigned char* __restrict__ Af8,
                                                  const unsigned char* __restrict__ Ytf8,
                                                  const _Float16* __restrict__ Yr,
                                                  const float* __restrict__ s,
                                                  float* __restrict__ T,
                                                  unsigned int* __restrict__ cnt,
                                                  float* __restrict__ out) {
    __shared__ long AsL[3 * ABYTES / 8];   // 48 KB
    __shared__ float red[16];
    __shared__ int islast;
    char* As8 = (char*)AsL;

    const int ib = blockIdx.x & 31;    // 32 I-tiles (fastest)
    const int jb = blockIdx.x >> 5;    // 8 K-chunks
    const int I0 = ib * BM;
    const int K0 = jb * KC;
    const int t   = threadIdx.x;
    const int w   = t >> 6;            // 0..15
    const int wm  = w >> 1;            // 32-row stripe (0..7)
    const int wn  = w & 1;             // 128-col half
    const int l   = t & 63;
    const int ln  = l & 31;
    const int lkh = l >> 5;

    f32x16 acc[4];
    #pragma unroll
    for (int q = 0; q < 4; ++q) acc[q] = (f32x16)(0.f);

    // Stage A subchunk SC into buffer B: 1 shot/wave (16 rows x 64 B).
    // Linear LDS dest; source 16B-group pre-swizzled by g ^ ((row>>1)&3).
    #define STAGE(SC, B)                                                       \
    {   const int kc = K0 + (SC) * SK;                                         \
        const int rr = w * 16 + (l >> 2);                                      \
        const int sg = ((l & 3) ^ ((rr >> 1) & 3)) * 16;                       \
        __builtin_amdgcn_global_load_lds(                                      \
            (const AS1 unsigned int*)(Af8 + (size_t)(I0 + rr) * Nn + kc + sg), \
            (AS3 unsigned int*)(As8 + (B) * ABYTES + w * 1024), 16, 0, 0);     \
    }

    STAGE(0, 0);
    STAGE(1, 1);
    WAITV(1);
    __builtin_amdgcn_s_barrier();

    const int r  = wm * 32 + ln;
    const int xA = ((r >> 1) & 3) << 1;

    for (int sc = 0; sc < NSC; ++sc) {
        const int cb = sc % 3;
        const long* Al = reinterpret_cast<const long*>(As8 + cb * ABYTES);
        long af[4];
        #pragma unroll
        for (int ks = 0; ks < 4; ++ks) af[ks] = Al[r * 8 + ((ks * 2 + lkh) ^ xA)];

        const unsigned char* ybase =
            Ytf8 + (size_t)(wn * 128 + ln) * Nn + K0 + sc * SK + lkh * 8;

        #define LOADB(D, TN)                                                   \
        {   const unsigned char* yp = ybase + (size_t)(TN) * 32 * Nn;          \
            D[0] = *reinterpret_cast<const long*>(yp);                         \
            D[1] = *reinterpret_cast<const long*>(yp + 16);                    \
            D[2] = *reinterpret_cast<const long*>(yp + 32);                    \
            D[3] = *reinterpret_cast<const long*>(yp + 48);                    \
        }

        long b0[4], b1[4];
        LOADB(b0, 0);
        #pragma unroll
        for (int tn = 0; tn < 4; ++tn) {
            if (tn < 3) { LOADB(b1, tn + 1); }
            else if (sc + 2 < NSC) { STAGE(sc + 2, (sc + 2) % 3); }  // last VMEM
            #pragma unroll
            for (int ks = 0; ks < 4; ++ks)
                acc[tn] = __builtin_amdgcn_mfma_f32_32x32x16_fp8_fp8(af[ks], b0[ks], acc[tn], 0, 0, 0);
            if (tn < 3) { b0[0]=b1[0]; b0[1]=b1[1]; b0[2]=b1[2]; b0[3]=b1[3]; }
        }
        #undef LOADB
        if (sc + 1 < NSC) __builtin_amdgcn_s_barrier();
    }
    #undef STAGE

    // epilogue: part = sum over held (64*W)[i][n] * Y[i][n]; 1/64 at the end
    float part = 0.f;
    #pragma unroll
    for (int tn = 0; tn < 4; ++tn) {
        const int n = wn * 128 + tn * 32 + ln;
        #pragma unroll
        for (int rr = 0; rr < 16; ++rr) {
            const int i = I0 + wm * 32 + (rr & 3) + 8 * (rr >> 2) + 4 * lkh;
            part += acc[tn][rr] * (float)Yr[(size_t)i * Dd + n];
        }
    }
    #pragma unroll
    for (int off = 32; off > 0; off >>= 1) part += __shfl_down(part, off, 64);
    if (l == 0) red[w] = part;
    __syncthreads();
    if (t == 0) {
        float tt = 0.f;
        #pragma unroll
        for (int i = 0; i < 16; ++i) tt += red[i];
        atomicAdd(T, tt * 0.015625f);   // 1/64
    }

    // ticket finalize (absorbs k_final)
    __threadfence();
    if (t == 0) islast = (atomicAdd(cnt, 1u) == (unsigned)(gridDim.x - 1)) ? 1 : 0;
    __syncthreads();
    if (islast) {
        float p = 0.f;
        if (t < 256) { const float sv = s[t]; p = sv * sv; }
        #pragma unroll
        for (int off = 32; off > 0; off >>= 1) p += __shfl_down(p, off, 64);
        if (l == 0) red[w] = p;
        __syncthreads();
        if (t == 0) {
            float ss = 0.f;
            #pragma unroll
            for (int i = 0; i < 16; ++i) ss += red[i];
            const float Tv = atomicAdd(T, 0.f);
            out[0] = -Tv;
            out[1] = ss - Tv;
        }
    }
}

// ---------------------------------------------------------------------------
extern "C" void kernel_launch(void* const* d_in, const int* in_sizes, int n_in,
                              void* d_out, int out_size, void* d_ws, size_t ws_size,
                              hipStream_t stream) {
    const float* Z = (const float*)d_in[1];
    const float* A = (const float*)d_in[2];
    float* out = (float*)d_out;

    char* ws = (char*)d_ws;
    float*         dis  = (float*)(ws);                          // 32 KB
    float*         rd   = (float*)(ws + 32768);                  // 32 KB
    float*         s    = (float*)(ws + 65536);                  // 1 KB
    float*         T    = (float*)(ws + 66560);                  // 4 B
    unsigned int*  cnt  = (unsigned int*)(ws + 66564);           // 4 B
    _Float16*      Yr   = (_Float16*)(ws + 131072);              // 4 MB [8192][256]
    unsigned char* Ytf8 = (unsigned char*)(ws + 131072 + (size_t)Nn * Dd * 2);  // 2 MB
    unsigned char* Af8  = (unsigned char*)(ws + 131072 + (size_t)Nn * Dd * 3);  // 64 MB

    k_rowcvt<<<Nn / 4, 256, 0, stream>>>(A, Af8, dis, rd, s, T, cnt);
    k_makeYt<<<Nn / 64, 256, 0, stream>>>(Z, dis, Ytf8, Yr);
    k_colsum<<<Nn / 256, 256, 0, stream>>>(Yr, rd, s);
    k_main<<<(Nn / BM) * (Nn / KC), 1024, 0, stream>>>(Af8, Ytf8, Yr, s, T, cnt, out);
}

// Round 14
// 197.093 us; speedup vs baseline: 1.3353x; 1.3353x over previous
//
#include <hip/hip_runtime.h>
#include <hip/hip_fp16.h>

typedef _Float16 f16x4  __attribute__((ext_vector_type(4)));
typedef float    f32x16 __attribute__((ext_vector_type(16)));

constexpr int Nn = 8192;
constexpr int Dd = 256;

constexpr int BM  = 256;        // I-rows per GEMM block
constexpr int KC  = 1024;       // K range per block
constexpr int SK  = 64;         // staged K subchunk (64 B/row)
constexpr int NSC = KC / SK;    // 16 subchunks
constexpr int NB  = 4;          // LDS buffers, stage 3 ahead
constexpr int ABYTES = BM * SK; // 16 KB per A buffer (fp8)
constexpr int YBYTES = Dd * SK; // 16 KB per Yt buffer (fp8)

#define AS1 __attribute__((address_space(1)))
#define AS3 __attribute__((address_space(3)))
#define WAITV(N) asm volatile("s_waitcnt vmcnt(" #N ")" ::: "memory")

// ---------------------------------------------------------------------------
// K1: rowsum of A -> dis = rsqrt(sum+1e-10), rd = sqrt(sum+1e-10);
//     writes Af8 = e4m3(A) (64 MB). Zeroes s/T/cnt. At BW floor (~6.27 TB/s).
__global__ __launch_bounds__(256) void k_rowcvt(const float* __restrict__ A,
                                                unsigned char* __restrict__ Af8,
                                                float* __restrict__ dis,
                                                float* __restrict__ rd,
                                                float* __restrict__ s,
                                                float* __restrict__ T,
                                                unsigned int* __restrict__ cnt) {
    if (blockIdx.x == 0) {
        if (threadIdx.x == 0) { *T = 0.f; *cnt = 0u; }
        s[threadIdx.x] = 0.f;
    }
    const int row  = blockIdx.x * 4 + (threadIdx.x >> 6);
    const int lane = threadIdx.x & 63;
    const float4*  rp = reinterpret_cast<const float4*>(A + (size_t)row * Nn);
    unsigned int*  wp = reinterpret_cast<unsigned int*>(Af8 + (size_t)row * Nn);
    float sum = 0.f;
    #pragma unroll
    for (int i = 0; i < Nn / 256; ++i) {
        float4 v = rp[i * 64 + lane];
        sum += (v.x + v.y) + (v.z + v.w);
        int p = __builtin_amdgcn_cvt_pk_fp8_f32(v.x, v.y, 0, false);
        p     = __builtin_amdgcn_cvt_pk_fp8_f32(v.z, v.w, p, true);
        wp[i * 64 + lane] = (unsigned int)p;
    }
    #pragma unroll
    for (int off = 32; off > 0; off >>= 1) sum += __shfl_down(sum, off, 64);
    if (lane == 0) {
        float rs = sum + 1e-10f;
        dis[row] = rsqrtf(rs);
        rd[row]  = sqrtf(rs);
    }
}

// ---------------------------------------------------------------------------
// K2: Y = dis * Z/||Z||. Writes Ytf8[256 n][8192 i] = e4m3(64*Y), Yr[8192][256]
//     f16 (true Y, epilogue), and colsum partials s[k] += rd*Y (absorbed K2b).
__global__ __launch_bounds__(256) void k_makeYt(const float* __restrict__ Z,
                                               const float* __restrict__ dis,
                                               const float* __restrict__ rd,
                                               unsigned char* __restrict__ Ytf8,
                                               _Float16* __restrict__ Yr,
                                               float* __restrict__ s) {
    __shared__ float nrm[64][4];
    __shared__ float sacc[Dd];
    __shared__ unsigned char tile[Dd][80];
    const int t = threadIdx.x;
    const int r = t >> 2, q = t & 3;
    const int row = blockIdx.x * 64 + r;
    if (t < Dd) sacc[t] = 0.f;
    const float4* zp = reinterpret_cast<const float4*>(Z + (size_t)row * Dd + q * 64);
    float4 v[16];
    float ss = 0.f;
    #pragma unroll
    for (int i = 0; i < 16; ++i) {
        v[i] = zp[i];
        ss += v[i].x*v[i].x + v[i].y*v[i].y + v[i].z*v[i].z + v[i].w*v[i].w;
    }
    nrm[r][q] = ss;
    __syncthreads();
    const float tot  = nrm[r][0] + nrm[r][1] + nrm[r][2] + nrm[r][3];
    const float sc   = dis[row] / fmaxf(sqrtf(tot), 1e-12f);
    const float sc8  = 64.f * sc;
    const float rdv  = rd[row];
    #pragma unroll
    for (int i = 0; i < 16; ++i) {
        const int c0 = q * 64 + i * 4;
        const float y0 = v[i].x * sc, y1 = v[i].y * sc,
                    y2 = v[i].z * sc, y3 = v[i].w * sc;
        *reinterpret_cast<f16x4*>(Yr + (size_t)row * Dd + c0) =
            f16x4{ (_Float16)y0, (_Float16)y1, (_Float16)y2, (_Float16)y3 };
        int p = __builtin_amdgcn_cvt_pk_fp8_f32(v[i].x * sc8, v[i].y * sc8, 0, false);
        p     = __builtin_amdgcn_cvt_pk_fp8_f32(v[i].z * sc8, v[i].w * sc8, p, true);
        tile[c0+0][r] = (unsigned char)(p);
        tile[c0+1][r] = (unsigned char)(p >> 8);
        tile[c0+2][r] = (unsigned char)(p >> 16);
        tile[c0+3][r] = (unsigned char)(p >> 24);
        atomicAdd(&sacc[c0+0], rdv * y0);
        atomicAdd(&sacc[c0+1], rdv * y1);
        atomicAdd(&sacc[c0+2], rdv * y2);
        atomicAdd(&sacc[c0+3], rdv * y3);
    }
    __syncthreads();
    int4*       dst = reinterpret_cast<int4*>(Ytf8 + (size_t)t * Nn + blockIdx.x * 64);
    const int4* src = reinterpret_cast<const int4*>(&tile[t][0]);
    #pragma unroll
    for (int i = 0; i < 4; ++i) dst[i] = src[i];
    if (t < Dd) atomicAdd(&s[t], sacc[t]);
}

// ---------------------------------------------------------------------------
// K3: T += sum_i Y_i . (A[I,Kchunk] @ Y[Kchunk])   [32x32x16 fp8 MFMA]
// r10-verbatim structure (best measured): SK=64, NB=4, stage 3 ahead,
// counted vmcnt(4), 16B-XOR swizzle, BM=256, 1024 thr, ib-fastest grid.
// Ticket finalize absorbed (was k_final). Yt holds 64*Y -> 1/64 at end.
__global__ __launch_bounds__(1024, 4) void k_main(const unsigned char* __restrict__ Af8,
                                                  const unsigned char* __restrict__ Ytf8,
                                                  const _Float16* __restrict__ Yr,
                                                  const float* __restrict__ s,
                                                  float* __restrict__ T,
                                                  unsigned int* __restrict__ cnt,
                                                  float* __restrict__ out) {
    __shared__ long As[NB * ABYTES / 8];    // 64 KB
    __shared__ long Ys[NB * YBYTES / 8];    // 64 KB
    __shared__ float red[16];
    __shared__ int islast;
    char* As8 = (char*)As;
    char* Ys8 = (char*)Ys;

    const int ib = blockIdx.x & (Nn / BM - 1);   // 32 I-tiles (fastest)
    const int jb = blockIdx.x >> 5;              // 8 K-chunks
    const int I0 = ib * BM;
    const int K0 = jb * KC;
    const int t   = threadIdx.x;
    const int w   = t >> 6;            // 0..15
    const int wm  = w >> 1;            // 32-row stripe (0..7)
    const int wn  = w & 1;             // 128-col half
    const int l   = t & 63;
    const int ln  = l & 31;
    const int lkh = l >> 5;

    f32x16 acc[4];
    #pragma unroll
    for (int q = 0; q < 4; ++q) acc[q] = (f32x16)(0.f);

    #define STAGE(SC, B)                                                       \
    {   const int kc = K0 + (SC) * SK;                                         \
        const int rr = w * 16 + (l >> 2);                                      \
        const int sg = ((l & 3) ^ ((rr >> 1) & 3)) * 16;                       \
        __builtin_amdgcn_global_load_lds(                                      \
            (const AS1 unsigned int*)(Af8 + (size_t)(I0 + rr) * Nn + kc + sg), \
            (AS3 unsigned int*)(As8 + (B) * ABYTES + w * 1024), 16, 0, 0);     \
        __builtin_amdgcn_global_load_lds(                                      \
            (const AS1 unsigned int*)(Ytf8 + (size_t)rr * Nn + kc + sg),       \
            (AS3 unsigned int*)(Ys8 + (B) * YBYTES + w * 1024), 16, 0, 0);     \
    }

    STAGE(0, 0); STAGE(1, 1); STAGE(2, 2);

    for (int sc = 0; sc < NSC; ++sc) {
        const int ah = NSC - 1 - sc;
        if (ah >= 2) WAITV(4); else if (ah == 1) WAITV(2); else WAITV(0);
        __builtin_amdgcn_s_barrier();
        if (sc + 3 < NSC) STAGE(sc + 3, (sc + 3) & 3);

        const int cb = sc & 3;
        const long* Al = reinterpret_cast<const long*>(As8 + cb * ABYTES);
        const long* Yl = reinterpret_cast<const long*>(Ys8 + cb * YBYTES);
        const int r  = wm * 32 + ln;
        const int xA = ((r >> 1) & 3) << 1;
        long af[4];
        #pragma unroll
        for (int ks = 0; ks < 4; ++ks) af[ks] = Al[r * 8 + ((ks * 2 + lkh) ^ xA)];
        #pragma unroll
        for (int tn = 0; tn < 4; ++tn) {
            const int n  = wn * 128 + tn * 32 + ln;
            const int xN = ((n >> 1) & 3) << 1;
            #pragma unroll
            for (int ks = 0; ks < 4; ++ks) {
                const long bf = Yl[n * 8 + ((ks * 2 + lkh) ^ xN)];
                acc[tn] = __builtin_amdgcn_mfma_f32_32x32x16_fp8_fp8(af[ks], bf, acc[tn], 0, 0, 0);
            }
        }
    }
    #undef STAGE

    // epilogue: part = sum over held (64*W)[i][n] * Y[i][n]; 1/64 at the end
    float part = 0.f;
    #pragma unroll
    for (int tn = 0; tn < 4; ++tn) {
        const int n = wn * 128 + tn * 32 + ln;
        #pragma unroll
        for (int rr = 0; rr < 16; ++rr) {
            const int i = I0 + wm * 32 + (rr & 3) + 8 * (rr >> 2) + 4 * lkh;
            part += acc[tn][rr] * (float)Yr[(size_t)i * Dd + n];
        }
    }
    #pragma unroll
    for (int off = 32; off > 0; off >>= 1) part += __shfl_down(part, off, 64);
    if (l == 0) red[w] = part;
    __syncthreads();
    if (t == 0) {
        float tt = 0.f;
        #pragma unroll
        for (int i = 0; i < 16; ++i) tt += red[i];
        atomicAdd(T, tt * 0.015625f);   // 1/64
    }

    // ticket finalize (absorbs k_final; validated r12/r13)
    __threadfence();
    if (t == 0) islast = (atomicAdd(cnt, 1u) == (unsigned)(gridDim.x - 1)) ? 1 : 0;
    __syncthreads();
    if (islast) {
        float p = 0.f;
        if (t < 256) { const float sv = s[t]; p = sv * sv; }
        #pragma unroll
        for (int off = 32; off > 0; off >>= 1) p += __shfl_down(p, off, 64);
        if (l == 0) red[w] = p;
        __syncthreads();
        if (t == 0) {
            float ss = 0.f;
            #pragma unroll
            for (int i = 0; i < 16; ++i) ss += red[i];
            const float Tv = atomicAdd(T, 0.f);
            out[0] = -Tv;
            out[1] = ss - Tv;
        }
    }
}

// ---------------------------------------------------------------------------
extern "C" void kernel_launch(void* const* d_in, const int* in_sizes, int n_in,
                              void* d_out, int out_size, void* d_ws, size_t ws_size,
                              hipStream_t stream) {
    const float* Z = (const float*)d_in[1];
    const float* A = (const float*)d_in[2];
    float* out = (float*)d_out;

    char* ws = (char*)d_ws;
    float*         dis  = (float*)(ws);                          // 32 KB
    float*         rd   = (float*)(ws + 32768);                  // 32 KB
    float*         s    = (float*)(ws + 65536);                  // 1 KB
    float*         T    = (float*)(ws + 66560);                  // 4 B
    unsigned int*  cnt  = (unsigned int*)(ws + 66564);           // 4 B
    _Float16*      Yr   = (_Float16*)(ws + 131072);              // 4 MB [8192][256]
    unsigned char* Ytf8 = (unsigned char*)(ws + 131072 + (size_t)Nn * Dd * 2);  // 2 MB
    unsigned char* Af8  = (unsigned char*)(ws + 131072 + (size_t)Nn * Dd * 3);  // 64 MB

    k_rowcvt<<<Nn / 4, 256, 0, stream>>>(A, Af8, dis, rd, s, T, cnt);
    k_makeYt<<<Nn / 64, 256, 0, stream>>>(Z, dis, rd, Ytf8, Yr, s);
    k_main<<<(Nn / BM) * (Nn / KC), 1024, 0, stream>>>(Af8, Ytf8, Yr, s, T, cnt, out);
}

// Round 15
// 127.307 us; speedup vs baseline: 2.0673x; 1.5482x over previous
//
#include <hip/hip_runtime.h>
#include <hip/hip_fp16.h>

typedef _Float16 f16x4  __attribute__((ext_vector_type(4)));
typedef float    f32x16 __attribute__((ext_vector_type(16)));

constexpr int Nn = 8192;
constexpr int Dd = 256;

constexpr int BM  = 256;        // I-rows per block
constexpr int KC  = 1024;       // K range per block
constexpr int SK  = 64;         // staged K subchunk (64 B/row = HBM granule)
constexpr int NSC = KC / SK;    // 16 subchunks
constexpr int NB  = 4;          // LDS buffers, stage 3 ahead
constexpr int ABYTES = BM * SK; // 16 KB per A buffer (fp8)
constexpr int YBYTES = Dd * SK; // 16 KB per Yt buffer (fp8)

#define AS1 __attribute__((address_space(1)))
#define AS3 __attribute__((address_space(3)))

// ---------------------------------------------------------------------------
// K1: rowsum of A -> dis = rsqrt(sum+1e-10), rd = sqrt(sum+1e-10);
//     ALSO writes Af8 = e4m3(A) (64 MB) for the fp8 pass 2.
//     Zeroes T and s (ws is poisoned 0xAA before timing).
__global__ __launch_bounds__(256) void k_rowcvt(const float* __restrict__ A,
                                                unsigned char* __restrict__ Af8,
                                                float* __restrict__ dis,
                                                float* __restrict__ rd,
                                                float* __restrict__ s,
                                                float* __restrict__ T) {
    if (blockIdx.x == 0) {
        if (threadIdx.x == 0) *T = 0.f;
        s[threadIdx.x] = 0.f;   // 256 threads cover s[0..255]
    }
    const int row  = blockIdx.x * 4 + (threadIdx.x >> 6);
    const int lane = threadIdx.x & 63;
    const float4*  rp = reinterpret_cast<const float4*>(A + (size_t)row * Nn);
    unsigned int*  wp = reinterpret_cast<unsigned int*>(Af8 + (size_t)row * Nn);
    float sum = 0.f;
    #pragma unroll
    for (int i = 0; i < Nn / 256; ++i) {
        float4 v = rp[i * 64 + lane];
        sum += (v.x + v.y) + (v.z + v.w);
        int p = __builtin_amdgcn_cvt_pk_fp8_f32(v.x, v.y, 0, false);
        p     = __builtin_amdgcn_cvt_pk_fp8_f32(v.z, v.w, p, true);
        wp[i * 64 + lane] = (unsigned int)p;
    }
    #pragma unroll
    for (int off = 32; off > 0; off >>= 1) sum += __shfl_down(sum, off, 64);
    if (lane == 0) {
        float rs = sum + 1e-10f;
        dis[row] = rsqrtf(rs);
        rd[row]  = sqrtf(rs);
    }
}

// ---------------------------------------------------------------------------
// K2: Y = dis * Z/||Z||. Writes Ytf8[256 n][8192 i] = e4m3(64*Y) (k-major,
//     GEMM B operand) and Yr[8192][256] f16 (true Y, for epilogue + colsum).
__global__ __launch_bounds__(256) void k_makeYt(const float* __restrict__ Z,
                                               const float* __restrict__ dis,
                                               unsigned char* __restrict__ Ytf8,
                                               _Float16* __restrict__ Yr) {
    __shared__ float nrm[64][4];
    __shared__ unsigned char tile[Dd][80];   // stride 80: 16B-aligned rows
    const int t = threadIdx.x;
    const int r = t >> 2, q = t & 3;
    const int row = blockIdx.x * 64 + r;
    const float4* zp = reinterpret_cast<const float4*>(Z + (size_t)row * Dd + q * 64);
    float4 v[16];
    float ss = 0.f;
    #pragma unroll
    for (int i = 0; i < 16; ++i) {
        v[i] = zp[i];
        ss += v[i].x*v[i].x + v[i].y*v[i].y + v[i].z*v[i].z + v[i].w*v[i].w;
    }
    nrm[r][q] = ss;
    __syncthreads();
    const float tot  = nrm[r][0] + nrm[r][1] + nrm[r][2] + nrm[r][3];
    const float sc   = dis[row] / fmaxf(sqrtf(tot), 1e-12f);   // true Y scale
    const float sc8  = 64.f * sc;                              // fp8 scale
    #pragma unroll
    for (int i = 0; i < 16; ++i) {
        const int c0 = q * 64 + i * 4;
        f16x4 y = { (_Float16)(v[i].x * sc), (_Float16)(v[i].y * sc),
                    (_Float16)(v[i].z * sc), (_Float16)(v[i].w * sc) };
        *reinterpret_cast<f16x4*>(Yr + (size_t)row * Dd + c0) = y;
        int p = __builtin_amdgcn_cvt_pk_fp8_f32(v[i].x * sc8, v[i].y * sc8, 0, false);
        p     = __builtin_amdgcn_cvt_pk_fp8_f32(v[i].z * sc8, v[i].w * sc8, p, true);
        tile[c0+0][r] = (unsigned char)(p);
        tile[c0+1][r] = (unsigned char)(p >> 8);
        tile[c0+2][r] = (unsigned char)(p >> 16);
        tile[c0+3][r] = (unsigned char)(p >> 24);
    }
    __syncthreads();
    int4*       dst = reinterpret_cast<int4*>(Ytf8 + (size_t)t * Nn + blockIdx.x * 64);
    const int4* src = reinterpret_cast<const int4*>(&tile[t][0]);
    #pragma unroll
    for (int i = 0; i < 4; ++i) dst[i] = src[i];
}

// ---------------------------------------------------------------------------
// K2b: s[k] = sum_j Zn[j][k] = sum_j Yr[j][k] * rd[j]   (f16 path, coalesced)
__global__ __launch_bounds__(256) void k_colsum(const _Float16* __restrict__ Yr,
                                                const float* __restrict__ rd,
                                                float* __restrict__ s) {
    const int c  = threadIdx.x;
    const int r0 = blockIdx.x * 256;
    float acc = 0.f;
    const _Float16* yp = Yr + (size_t)r0 * Dd + c;
    #pragma unroll 8
    for (int r = 0; r < 256; ++r) acc += (float)yp[(size_t)r * Dd] * rd[r0 + r];
    atomicAdd(&s[c], acc);
}

// ---------------------------------------------------------------------------
// K3: T += sum_i Y_i . (A[I,Kchunk] @ Y[Kchunk])   [32x32x16 fp8 MFMA]
// Round-10 structure (best measured): SK=64, NB=4, stage 3 ahead, counted
// vmcnt(4), 16B-preserving XOR swizzle, BM=256, 1024 thr, ib-fastest grid.
// fp8 32x32x16 fragments: A row=l&31, k=(l>>5)*8+byte; B col=l&31 same k;
// D col=l&31, row=(reg&3)+8*(reg>>2)+4*(l>>5) (shape-determined, m101).
// Yt holds 64*Y -> acc = 64*W; epilogue atomicAdd scales by 1/64.
__global__ __launch_bounds__(1024, 4) void k_main(const unsigned char* __restrict__ Af8,
                                                  const unsigned char* __restrict__ Ytf8,
                                                  const _Float16* __restrict__ Yr,
                                                  float* __restrict__ T) {
    __shared__ long As[NB * ABYTES / 8];    // 64 KB
    __shared__ long Ys[NB * YBYTES / 8];    // 64 KB
    char* As8 = (char*)As;
    char* Ys8 = (char*)Ys;

    const int ib = blockIdx.x & (Nn / BM - 1);   // 32 I-tiles (fastest)
    const int jb = blockIdx.x >> 5;              // 8 K-chunks
    const int I0 = ib * BM;
    const int K0 = jb * KC;
    const int t   = threadIdx.x;
    const int w   = t >> 6;            // 0..15
    const int wm  = w >> 1;            // 32-row stripe (0..7)
    const int wn  = w & 1;             // 128-col half
    const int l   = t & 63;
    const int ln  = l & 31;
    const int lkh = l >> 5;

    f32x16 acc[4];
    #pragma unroll
    for (int q = 0; q < 4; ++q) acc[q] = (f32x16)(0.f);

    // Stage subchunk SC into buffer B: per wave 1 A-shot + 1 Yt-shot (1 KB
    // each; 16 rows x 64 B). Linear LDS dest; source 16B-group pre-swizzled
    // by s ^ ((row>>1)&3) (matches the even-XOR read swizzle).
    #define STAGE(SC, B)                                                       \
    {   const int kc = K0 + (SC) * SK;                                         \
        const int rr = w * 16 + (l >> 2);                                      \
        const int sg = ((l & 3) ^ ((rr >> 1) & 3)) * 16;                       \
        __builtin_amdgcn_global_load_lds(                                      \
            (const AS1 unsigned int*)(Af8 + (size_t)(I0 + rr) * Nn + kc + sg), \
            (AS3 unsigned int*)(As8 + (B) * ABYTES + w * 1024), 16, 0, 0);     \
        __builtin_amdgcn_global_load_lds(                                      \
            (const AS1 unsigned int*)(Ytf8 + (size_t)rr * Nn + kc + sg),       \
            (AS3 unsigned int*)(Ys8 + (B) * YBYTES + w * 1024), 16, 0, 0);     \
    }

    #define WAITV(N) asm volatile("s_waitcnt vmcnt(" #N ")" ::: "memory")

    STAGE(0, 0); STAGE(1, 1); STAGE(2, 2);

    for (int sc = 0; sc < NSC; ++sc) {
        const int ah = NSC - 1 - sc;
        if (ah >= 2) WAITV(4); else if (ah == 1) WAITV(2); else WAITV(0);
        __builtin_amdgcn_s_barrier();
        if (sc + 3 < NSC) STAGE(sc + 3, (sc + 3) & 3);

        const int cb = sc & 3;
        const long* Al = reinterpret_cast<const long*>(As8 + cb * ABYTES);
        const long* Yl = reinterpret_cast<const long*>(Ys8 + cb * YBYTES);
        const int r  = wm * 32 + ln;
        const int xA = ((r >> 1) & 3) << 1;
        long af[4];
        #pragma unroll
        for (int ks = 0; ks < 4; ++ks) af[ks] = Al[r * 8 + ((ks * 2 + lkh) ^ xA)];
        #pragma unroll
        for (int tn = 0; tn < 4; ++tn) {
            const int n  = wn * 128 + tn * 32 + ln;
            const int xN = ((n >> 1) & 3) << 1;
            #pragma unroll
            for (int ks = 0; ks < 4; ++ks) {
                const long bf = Yl[n * 8 + ((ks * 2 + lkh) ^ xN)];
                acc[tn] = __builtin_amdgcn_mfma_f32_32x32x16_fp8_fp8(af[ks], bf, acc[tn], 0, 0, 0);
            }
        }
    }

    // epilogue: part = sum over held (64*W)[i][n] * Y[i][n]; scale 1/64 at end
    float part = 0.f;
    #pragma unroll
    for (int tn = 0; tn < 4; ++tn) {
        const int n = wn * 128 + tn * 32 + ln;
        #pragma unroll
        for (int rr = 0; rr < 16; ++rr) {
            const int i = I0 + wm * 32 + (rr & 3) + 8 * (rr >> 2) + 4 * lkh;
            part += acc[tn][rr] * (float)Yr[(size_t)i * Dd + n];
        }
    }
    #pragma unroll
    for (int off = 32; off > 0; off >>= 1) part += __shfl_down(part, off, 64);
    __shared__ float red[16];
    if (l == 0) red[w] = part;
    __syncthreads();
    if (threadIdx.x == 0) {
        float tt = 0.f;
        #pragma unroll
        for (int i = 0; i < 16; ++i) tt += red[i];
        atomicAdd(T, tt * 0.015625f);   // 1/64
    }
}

// ---------------------------------------------------------------------------
// K4: out[0] = homo = -T ; out[1] = hetero = ||s||^2 - T
__global__ __launch_bounds__(256) void k_final(const float* __restrict__ s,
                                               const float* __restrict__ T,
                                               float* __restrict__ out) {
    const int t = threadIdx.x;
    float v = s[t];
    float p = v * v;
    #pragma unroll
    for (int off = 32; off > 0; off >>= 1) p += __shfl_down(p, off, 64);
    __shared__ float red[4];
    if ((t & 63) == 0) red[t >> 6] = p;
    __syncthreads();
    if (t == 0) {
        const float ss = red[0] + red[1] + red[2] + red[3];
        const float Tv = *T;
        out[0] = -Tv;
        out[1] = ss - Tv;
    }
}

// ---------------------------------------------------------------------------
extern "C" void kernel_launch(void* const* d_in, const int* in_sizes, int n_in,
                              void* d_out, int out_size, void* d_ws, size_t ws_size,
                              hipStream_t stream) {
    const float* Z = (const float*)d_in[1];
    const float* A = (const float*)d_in[2];
    float* out = (float*)d_out;

    char* ws = (char*)d_ws;
    float*         dis  = (float*)(ws);                          // 32 KB
    float*         rd   = (float*)(ws + 32768);                  // 32 KB
    float*         s    = (float*)(ws + 65536);                  // 1 KB
    float*         T    = (float*)(ws + 66560);                  // 4 B
    _Float16*      Yr   = (_Float16*)(ws + 131072);              // 4 MB [8192][256]
    unsigned char* Ytf8 = (unsigned char*)(ws + 131072 + (size_t)Nn * Dd * 2);  // 2 MB
    unsigned char* Af8  = (unsigned char*)(ws + 131072 + (size_t)Nn * Dd * 3);  // 64 MB

    k_rowcvt<<<Nn / 4, 256, 0, stream>>>(A, Af8, dis, rd, s, T);
    k_makeYt<<<Nn / 64, 256, 0, stream>>>(Z, dis, Ytf8, Yr);
    k_colsum<<<Nn / 256, 256, 0, stream>>>(Yr, rd, s);
    k_main<<<(Nn / BM) * (Nn / KC), 1024, 0, stream>>>(Af8, Ytf8, Yr, T);
    k_final<<<1, 256, 0, stream>>>(s, T, out);
}